// Round 1
// baseline (554.937 us; speedup 1.0000x reference)
//
#include <hip/hip_runtime.h>
#include <hip/hip_bf16.h>

// TTCN: h=relu(X@W1+b1); h=relu(h@W2+b2); filt=h@W3+b3; masked softmax over Lx;
// out[n,k]=relu(sum_{l,d} X[n,l,d]*softmax(filt)[n,l,k,d] + T_bias[k])
// N=128, LX=512, D=32, K=63, C=D*K=2016.

#define N_   128
#define LX_  512
#define D_   32
#define K_   63
#define C_   2016

// ---------------- Kernel A: H = relu(relu(X@W1+b1)@W2+b2), stride-64 padded ----
__global__ __launch_bounds__(256) void kern_mlp(
    const float* __restrict__ X, const float* __restrict__ W1,
    const float* __restrict__ b1, const float* __restrict__ W2,
    const float* __restrict__ b2, float* __restrict__ H) {
  const int token = blockIdx.x * 256 + threadIdx.x;  // 65536 tokens
  const float* x = X + (size_t)token * D_;
  float xr[D_];
#pragma unroll
  for (int i = 0; i < D_; i += 4) {
    float4 v = *reinterpret_cast<const float4*>(x + i);
    xr[i] = v.x; xr[i + 1] = v.y; xr[i + 2] = v.z; xr[i + 3] = v.w;
  }
  float h1[K_];
#pragma unroll 1
  for (int jn = 0; jn < K_; ++jn) {
    float a = b1[jn];
#pragma unroll
    for (int i = 0; i < D_; ++i) a = fmaf(xr[i], W1[i * K_ + jn], a);
    h1[jn] = fmaxf(a, 0.f);
  }
  float* hrow = H + (size_t)token * 64;
#pragma unroll 1
  for (int jn = 0; jn < K_; ++jn) {
    float a = b2[jn];
#pragma unroll
    for (int t = 0; t < K_; ++t) a = fmaf(h1[t], W2[t * K_ + jn], a);
    hrow[jn] = fmaxf(a, 0.f);
  }
  hrow[63] = 0.f;  // zero pad so float4 tail reads are clean
}

// ---------------- Kernel B: fused layer3-GEMM + masked online softmax + pool ---
// One block per (n,k). Thread: j = tid&31 (the d channel), g = tid>>5 (row group).
// 8 chunks of 64 rows; per chunk each thread computes 8 logits (row l, channel
// c=k*32+j) and folds them into an online-softmax state (m, s, o=sum e*X[n,l,j]).
__global__ __launch_bounds__(256) void kern_att(
    const float* __restrict__ X, const float* __restrict__ Mk,
    const float* __restrict__ H, const float* __restrict__ W3,
    const float* __restrict__ b3, const float* __restrict__ Tb,
    float* __restrict__ out) {
  const int bid = blockIdx.x;
  const int n = bid / K_, k = bid % K_;
  const int tid = threadIdx.x;
  const int j = tid & 31, g = tid >> 5;

  // w3s: columns W3[:, k*32+j], bank-swizzled: logical t stored at col (t+4j)&63.
  // -> b128 reads across j land 2-way-conflict worst case (free, m136).
  __shared__ float w3s[32][64];
  __shared__ float Hs[64][68];   // stride 68: 16B-aligned rows, broadcast reads
  __shared__ float redm[8][32], reds[8][32], redo[8][32];

  for (int idx = tid; idx < 32 * 64; idx += 256) {
    const int jj = idx >> 6, tt = idx & 63;
    const int t = (tt - 4 * jj) & 63;          // logical t at physical col tt
    w3s[jj][tt] = (t < K_) ? W3[t * C_ + k * 32 + jj] : 0.f;
  }
  const float bj = b3[k * 32 + j];

  float m = -3.0e38f, s = 0.f, o = 0.f;

  for (int c = 0; c < 8; ++c) {
    __syncthreads();  // protect Hs from previous chunk's readers
#pragma unroll
    for (int it = 0; it < 4; ++it) {
      const int p = tid + it * 256;            // 0..1023 float4 slots
      const int row = p >> 4, q = p & 15;
      const float4 v = *reinterpret_cast<const float4*>(
          H + ((size_t)(n * LX_ + c * 64 + row)) * 64 + q * 4);
      *reinterpret_cast<float4*>(&Hs[row][q * 4]) = v;
    }
    __syncthreads();

    float acc[8];
#pragma unroll
    for (int r = 0; r < 8; ++r) acc[r] = 0.f;

#pragma unroll 4
    for (int t = 0; t < 64; t += 4) {
      const int col = (t + 4 * j) & 63;
      const float4 w = *reinterpret_cast<const float4*>(&w3s[j][col]);
#pragma unroll
      for (int r = 0; r < 8; ++r) {
        const float4 h = *reinterpret_cast<const float4*>(&Hs[g * 8 + r][t]);
        acc[r] = fmaf(w.x, h.x, acc[r]);
        acc[r] = fmaf(w.y, h.y, acc[r]);
        acc[r] = fmaf(w.z, h.z, acc[r]);
        acc[r] = fmaf(w.w, h.w, acc[r]);
      }
    }

#pragma unroll
    for (int r = 0; r < 8; ++r) {
      const int l = c * 64 + g * 8 + r;
      const float mk = Mk[n * LX_ + l];
      const float logit = fmaf(mk, acc[r] + bj, (1.f - mk) * (-1e8f));
      const float xv = X[((size_t)(n * LX_ + l)) * D_ + j];
      const float mn = fmaxf(m, logit);
      const float ea = __expf(m - mn);       // rescale old state
      const float eb = __expf(logit - mn);   // new element
      s = fmaf(s, ea, eb);
      o = fmaf(o, ea, eb * xv);
      m = mn;
    }
  }

  redm[g][j] = m; reds[g][j] = s; redo[g][j] = o;
  __syncthreads();

  if (tid < 32) {
    float M = -3.0e38f;
#pragma unroll
    for (int gg = 0; gg < 8; ++gg) M = fmaxf(M, redm[gg][tid]);
    float S = 0.f, O = 0.f;
#pragma unroll
    for (int gg = 0; gg < 8; ++gg) {
      const float e = __expf(redm[gg][tid] - M);
      S = fmaf(reds[gg][tid], e, S);
      O = fmaf(redo[gg][tid], e, O);
    }
    float val = O / S;  // per-d-channel weighted mean of X
#pragma unroll
    for (int off = 16; off > 0; off >>= 1)
      val += __shfl_down(val, off, 32);
    if (tid == 0) out[n * K_ + k] = fmaxf(val + Tb[k], 0.f);
  }
}

extern "C" void kernel_launch(void* const* d_in, const int* in_sizes, int n_in,
                              void* d_out, int out_size, void* d_ws, size_t ws_size,
                              hipStream_t stream) {
  const float* X  = (const float*)d_in[0];
  const float* Mk = (const float*)d_in[1];
  const float* W1 = (const float*)d_in[2];
  const float* b1 = (const float*)d_in[3];
  const float* W2 = (const float*)d_in[4];
  const float* b2 = (const float*)d_in[5];
  const float* W3 = (const float*)d_in[6];
  const float* b3 = (const float*)d_in[7];
  const float* Tb = (const float*)d_in[8];
  float* out = (float*)d_out;
  float* H = (float*)d_ws;  // 128*512*64 f32 = 16 MiB scratch

  kern_mlp<<<N_ * LX_ / 256, 256, 0, stream>>>(X, W1, b1, W2, b2, H);
  kern_att<<<N_ * K_, 256, 0, stream>>>(X, Mk, H, W3, b3, Tb, out);
}

// Round 2
// 145.370 us; speedup vs baseline: 3.8174x; 3.8174x over previous
//
#include <hip/hip_runtime.h>
#include <hip/hip_bf16.h>

// TTCN: h=relu(X@W1+b1); h=relu(h@W2+b2); filt=h@W3+b3; masked softmax over Lx;
// out[n,k]=relu(sum_{l,d} X[n,l,d]*softmax(filt)[n,l,k,d] + T_bias[k])
// N=128, LX=512, D=32, K=63, C=2016.
// Strategy: bf16 MFMA for all three GEMMs; softmax folded flash-style into the
// layer-3 GEMM epilogue (no max-subtraction: logits are O(1); masked rows get
// e = exp(logit)*mask = 0). Bias tricks: h1[63]=1 & W2 row63=b2; H[:,63]=1 &
// W3 row63=b3 -> biases ride inside the MFMA K-dim.

#define N_   128
#define LX_  512
#define D_   32
#define K_   63
#define C_   2016

typedef __bf16 bf16x8 __attribute__((ext_vector_type(8)));
typedef float floatx4 __attribute__((ext_vector_type(4)));

static __device__ __forceinline__ floatx4 mfma16(bf16x8 a, bf16x8 b, floatx4 c) {
  return __builtin_amdgcn_mfma_f32_16x16x32_bf16(a, b, c, 0, 0, 0);
}

// ---------------- Kernel A: H(bf16, 65536x64) = MLP(X), H[:,63]=1.0 ----------
// A-layout: A[m=lane&15][k=quad*8+j]; C/D: col=lane&15, row=quad*4+reg (m89).
__global__ __launch_bounds__(256) void kern_mlp(
    const float* __restrict__ X, const float* __restrict__ W1,
    const float* __restrict__ b1, const float* __restrict__ W2,
    const float* __restrict__ b2, __bf16* __restrict__ H) {
  __shared__ __bf16 W1T[64][40];      // [col j][k t], pad 40: bank stride 20 -> <=2-way
  __shared__ __bf16 W2T[64][72];      // [col c][k t], stride 144B -> bank stride 4
  __shared__ float b1s[64];
  __shared__ __bf16 h1s[4][16][72];   // per-wave h1 tile, row-major [m][k]

  const int tid = threadIdx.x;
  const int w = tid >> 6, lane = tid & 63, quad = lane >> 4, l16 = lane & 15;

  for (int idx = tid; idx < 32 * 64; idx += 256) {
    const int t = idx >> 6, j = idx & 63;
    W1T[j][t] = (__bf16)((j < K_) ? W1[t * K_ + j] : 0.f);
  }
  for (int idx = tid; idx < 64 * 64; idx += 256) {
    const int t = idx >> 6, c = idx & 63;
    float v;
    if (t < K_) v = (c < K_) ? W2[t * K_ + c] : 0.f;
    else        v = (c < K_) ? b2[c] : 1.f;   // row63 = bias; W2T[63][63]=1 keeps H[:,63]=1
    W2T[c][t] = (__bf16)v;
  }
  if (tid < 64) b1s[tid] = (tid < K_) ? b1[tid] : 0.f;
  __syncthreads();

  bf16x8 b1f[4], b2f[4][2];
  float b1v[4];
#pragma unroll
  for (int i = 0; i < 4; ++i) {
    b1f[i]    = *(const bf16x8*)&W1T[i * 16 + l16][quad * 8];
    b2f[i][0] = *(const bf16x8*)&W2T[i * 16 + l16][quad * 8];
    b2f[i][1] = *(const bf16x8*)&W2T[i * 16 + l16][32 + quad * 8];
    b1v[i] = b1s[i * 16 + l16];
  }

  const int blkbase = blockIdx.x * 256;
#pragma unroll 1
  for (int m4 = 0; m4 < 4; ++m4) {
    const int tok0 = blkbase + w * 64 + m4 * 16;
    // A1 fragment: X row (tok0+l16), k = quad*8 + 0..7 (K=32 exact)
    const float* xp = X + (size_t)(tok0 + l16) * D_ + quad * 8;
    const float4 xa = *(const float4*)xp;
    const float4 xb = *(const float4*)(xp + 4);
    bf16x8 a1;
    a1[0]=(__bf16)xa.x; a1[1]=(__bf16)xa.y; a1[2]=(__bf16)xa.z; a1[3]=(__bf16)xa.w;
    a1[4]=(__bf16)xb.x; a1[5]=(__bf16)xb.y; a1[6]=(__bf16)xb.z; a1[7]=(__bf16)xb.w;

    __syncthreads();  // WAR on h1s vs previous iteration's reads
#pragma unroll
    for (int i = 0; i < 4; ++i) {
      floatx4 acc = {0.f, 0.f, 0.f, 0.f};
      acc = mfma16(a1, b1f[i], acc);
#pragma unroll
      for (int r = 0; r < 4; ++r) {
        float v = fmaxf(acc[r] + b1v[i], 0.f);
        if (i == 3 && l16 == 15) v = 1.f;   // h1 col 63 := 1.0 (layer-2 bias row)
        h1s[w][quad * 4 + r][i * 16 + l16] = (__bf16)v;
      }
    }
    __syncthreads();

    const bf16x8 a20 = *(const bf16x8*)&h1s[w][l16][quad * 8];
    const bf16x8 a21 = *(const bf16x8*)&h1s[w][l16][32 + quad * 8];

#pragma unroll
    for (int i = 0; i < 4; ++i) {
      floatx4 acc = {0.f, 0.f, 0.f, 0.f};
      acc = mfma16(a20, b2f[i][0], acc);
      acc = mfma16(a21, b2f[i][1], acc);
#pragma unroll
      for (int r = 0; r < 4; ++r) {
        const float v = fmaxf(acc[r], 0.f);   // bias already in via k=63
        H[(size_t)(tok0 + quad * 4 + r) * 64 + i * 16 + l16] = (__bf16)v;
      }
    }
  }
}

// ---------------- Kernel B: fused logits-MFMA + exp/mask + pooling -----------
// Block = (n, 96-channel tile). 6 N-tiles, B-frags resident in VGPRs.
// Wave w handles rows it*64 + w*16 .. +15 each iteration.
__global__ __launch_bounds__(256) void kern_att(
    const float* __restrict__ X, const float* __restrict__ Mk,
    const __bf16* __restrict__ H, const float* __restrict__ W3,
    const float* __restrict__ b3, const float* __restrict__ Tb,
    float* __restrict__ out) {
  __shared__ __bf16 W3T[96][72];   // [c_local][k t], row63 = b3
  __shared__ float XsT[32][68];    // [d][row_local], 64 rows per outer iter
  __shared__ float redS[4][96], redO[4][96];
  __shared__ float rbuf[96];

  const int bid = blockIdx.x;
  const int n = bid / 21, bt = bid - n * 21;
  const int base = bt * 96;
  const int tid = threadIdx.x;
  const int w = tid >> 6, lane = tid & 63, quad = lane >> 4, l16 = lane & 15;

  for (int idx = tid; idx < 64 * 96; idx += 256) {
    const int t = idx / 96, c = idx - t * 96;
    const float v = (t < K_) ? W3[(size_t)t * C_ + base + c] : b3[base + c];
    W3T[c][t] = (__bf16)v;
  }
  __syncthreads();

  bf16x8 bf[6][2];
#pragma unroll
  for (int i = 0; i < 6; ++i) {
    bf[i][0] = *(const bf16x8*)&W3T[i * 16 + l16][quad * 8];
    bf[i][1] = *(const bf16x8*)&W3T[i * 16 + l16][32 + quad * 8];
  }

  float s[6] = {0, 0, 0, 0, 0, 0}, o[6] = {0, 0, 0, 0, 0, 0};

#pragma unroll 1
  for (int it = 0; it < 8; ++it) {
    const int l0 = it * 64;
    __syncthreads();  // WAR on XsT
#pragma unroll
    for (int u = 0; u < 2; ++u) {
      const int slot = tid + u * 256;            // 512 float4 slots = 64 rows x 32 d
      const int rowl = slot >> 3, dq = (slot & 7) * 4;
      const float4 v = *(const float4*)(X + (size_t)(n * LX_ + l0 + rowl) * D_ + dq);
      XsT[dq + 0][rowl] = v.x;
      XsT[dq + 1][rowl] = v.y;
      XsT[dq + 2][rowl] = v.z;
      XsT[dq + 3][rowl] = v.w;
    }
    __syncthreads();

    const int lw = l0 + w * 16;
    const __bf16* hp = H + (size_t)(n * LX_ + lw + l16) * 64;
    const bf16x8 a0 = *(const bf16x8*)(hp + quad * 8);
    const bf16x8 a1 = *(const bf16x8*)(hp + 32 + quad * 8);
    const float4 mk4 = *(const float4*)(Mk + n * LX_ + lw + quad * 4);

#pragma unroll
    for (int i = 0; i < 6; ++i) {
      floatx4 acc = {0.f, 0.f, 0.f, 0.f};
      acc = mfma16(a0, bf[i][0], acc);
      acc = mfma16(a1, bf[i][1], acc);   // logit incl. b3 (k=63 row, H[:,63]=1)
      const int d = (i * 16 + l16) & 31;  // base%32==0
      const float4 x4 = *(const float4*)&XsT[d][w * 16 + quad * 4];
      const float e0 = __expf(acc[0]) * mk4.x;
      const float e1 = __expf(acc[1]) * mk4.y;
      const float e2 = __expf(acc[2]) * mk4.z;
      const float e3 = __expf(acc[3]) * mk4.w;
      s[i] += (e0 + e1) + (e2 + e3);
      o[i] = fmaf(e0, x4.x, o[i]);
      o[i] = fmaf(e1, x4.y, o[i]);
      o[i] = fmaf(e2, x4.z, o[i]);
      o[i] = fmaf(e3, x4.w, o[i]);
    }
  }

  // reduce over the 4 quads (rows) within the wave
#pragma unroll
  for (int i = 0; i < 6; ++i) {
    s[i] += __shfl_xor(s[i], 16);
    s[i] += __shfl_xor(s[i], 32);
    o[i] += __shfl_xor(o[i], 16);
    o[i] += __shfl_xor(o[i], 32);
  }
  if (quad == 0) {
#pragma unroll
    for (int i = 0; i < 6; ++i) {
      redS[w][i * 16 + l16] = s[i];
      redO[w][i * 16 + l16] = o[i];
    }
  }
  __syncthreads();
  if (tid < 96) {
    const float S = redS[0][tid] + redS[1][tid] + redS[2][tid] + redS[3][tid];
    const float O = redO[0][tid] + redO[1][tid] + redO[2][tid] + redO[3][tid];
    rbuf[tid] = O / S;
  }
  __syncthreads();
  if (tid < 3) {
    float acc = 0.f;
#pragma unroll
    for (int dd = 0; dd < 32; ++dd) acc += rbuf[tid * 32 + dd];
    const int k = bt * 3 + tid;
    out[n * K_ + k] = fmaxf(acc + Tb[k], 0.f);
  }
}

extern "C" void kernel_launch(void* const* d_in, const int* in_sizes, int n_in,
                              void* d_out, int out_size, void* d_ws, size_t ws_size,
                              hipStream_t stream) {
  const float* X  = (const float*)d_in[0];
  const float* Mk = (const float*)d_in[1];
  const float* W1 = (const float*)d_in[2];
  const float* b1 = (const float*)d_in[3];
  const float* W2 = (const float*)d_in[4];
  const float* b2 = (const float*)d_in[5];
  const float* W3 = (const float*)d_in[6];
  const float* b3 = (const float*)d_in[7];
  const float* Tb = (const float*)d_in[8];
  float* out = (float*)d_out;
  __bf16* H = (__bf16*)d_ws;  // 65536 x 64 bf16 = 8 MiB

  kern_mlp<<<N_ * LX_ / 256, 256, 0, stream>>>(X, W1, b1, W2, b2, H);
  kern_att<<<N_ * 21, 256, 0, stream>>>(X, Mk, H, W3, b3, Tb, out);
}

// Round 3
// 128.752 us; speedup vs baseline: 4.3101x; 1.1291x over previous
//
#include <hip/hip_runtime.h>
#include <hip/hip_bf16.h>

// TTCN: h=relu(X@W1+b1); h=relu(h@W2+b2); filt=h@W3+b3; masked softmax over Lx;
// out[n,k]=relu(sum_{l,d} X[n,l,d]*softmax(filt)[n,l,k,d] + T_bias[k])
// N=128, LX=512, D=32, K=63, C=2016.
// R3: all weights pre-packed to MFMA frag layout in ws (kern_prep); kern_att is
// barrier-free (no steady-state LDS): H/X/Mk straight from global, 12 MFMA +
// exp epilogue per 64-row chunk. Bias tricks: h1[63]=1 & W2 row63=b2 => H[:,63]=1;
// W3fr row63=b3 => biases ride the MFMA K-dim.

#define N_   128
#define LX_  512
#define D_   32
#define K_   63
#define C_   2016

typedef __bf16 bf16x8 __attribute__((ext_vector_type(8)));
typedef float floatx4 __attribute__((ext_vector_type(4)));

static __device__ __forceinline__ floatx4 mfma16(bf16x8 a, bf16x8 b, floatx4 c) {
  return __builtin_amdgcn_mfma_f32_16x16x32_bf16(a, b, c, 0, 0, 0);
}

// ws layout (bytes)
#define H_OFF    0u                       // 65536 x 64 bf16 = 8 MiB, col63 == 1.0
#define W3FR_OFF (8u * 1024u * 1024u)     // 2016*64 bf16 frag-packed (row63 = b3)
#define W1FR_OFF (W3FR_OFF + 258048u)     // 2048 bf16
#define W2FR_OFF (W1FR_OFF + 4096u)       // 4096 bf16
#define B1_OFF   (W2FR_OFF + 8192u)       // 64 f32

// ---------------- prep: pack weights into MFMA B-fragment order --------------
// frag addr for lane(l16,quad), vgpr j: base + ((..tile/i/h..)*16 + l16)*32 + quad*8 + j
__global__ __launch_bounds__(256) void kern_prep(
    const float* __restrict__ W1, const float* __restrict__ b1,
    const float* __restrict__ W2, const float* __restrict__ b2,
    const float* __restrict__ W3, const float* __restrict__ b3,
    __bf16* __restrict__ W3fr, __bf16* __restrict__ W1fr,
    __bf16* __restrict__ W2fr, float* __restrict__ b1pad) {
  const int g = blockIdx.x * 256 + threadIdx.x;
  if (g < 129024) {                       // W3fr: [tile21][i6][h2][l16][quad][8]
    const int j = g & 7, quad = (g >> 3) & 3, l16 = (g >> 5) & 15, h = (g >> 9) & 1;
    const int rest = g >> 10, i = rest % 6, tile = rest / 6;
    const int c = tile * 96 + i * 16 + l16;
    const int t = h * 32 + quad * 8 + j;
    W3fr[g] = (__bf16)((t < K_) ? W3[(size_t)t * C_ + c] : b3[c]);
  } else if (g < 129024 + 2048) {         // W1fr: [i4][l16][quad][8]
    const int g2 = g - 129024;
    const int j = g2 & 7, quad = (g2 >> 3) & 3, l16 = (g2 >> 5) & 15, i = g2 >> 9;
    const int ch = i * 16 + l16, t = quad * 8 + j;
    W1fr[g2] = (__bf16)((ch < K_) ? W1[t * K_ + ch] : 0.f);
  } else if (g < 129024 + 2048 + 4096) {  // W2fr: [i4][h2][l16][quad][8], row63=b2, [63][63]=1
    const int g2 = g - 129024 - 2048;
    const int j = g2 & 7, quad = (g2 >> 3) & 3, l16 = (g2 >> 5) & 15, h = (g2 >> 9) & 1;
    const int i = g2 >> 10;
    const int ch = i * 16 + l16, t = h * 32 + quad * 8 + j;
    float v;
    if (t < K_) v = (ch < K_) ? W2[t * K_ + ch] : 0.f;
    else        v = (ch < K_) ? b2[ch] : 1.f;
    W2fr[g2] = (__bf16)v;
  } else if (g < 129024 + 2048 + 4096 + 64) {
    const int g2 = g - 129024 - 2048 - 4096;
    b1pad[g2] = (g2 < K_) ? b1[g2] : 0.f;
  }
}

// ---------------- Kernel A: H(bf16, 65536x64) = MLP(X), H[:,63]=1.0 ----------
// One 16-token tile per wave; single __syncthreads (h1s transpose round-trip).
__global__ __launch_bounds__(256) void kern_mlp(
    const float* __restrict__ X, const __bf16* __restrict__ W1fr,
    const __bf16* __restrict__ W2fr, const float* __restrict__ b1pad,
    __bf16* __restrict__ H) {
  __shared__ float h1s[4][16][68];   // per-wave transpose tile (f32: clean banks)
  const int tid = threadIdx.x;
  const int w = tid >> 6, lane = tid & 63, quad = lane >> 4, l16 = lane & 15;

  bf16x8 b1f[4], b2f[4][2];
  float b1v[4];
#pragma unroll
  for (int i = 0; i < 4; ++i) {
    b1f[i]    = *(const bf16x8*)(W1fr + ((i * 16 + l16) * 4 + quad) * 8);
    b2f[i][0] = *(const bf16x8*)(W2fr + (((i * 2 + 0) * 16 + l16) * 4 + quad) * 8);
    b2f[i][1] = *(const bf16x8*)(W2fr + (((i * 2 + 1) * 16 + l16) * 4 + quad) * 8);
    b1v[i] = b1pad[i * 16 + l16];
  }

  const int tok0 = blockIdx.x * 64 + w * 16;
  const float* xp = X + (size_t)(tok0 + l16) * D_ + quad * 8;
  const float4 xa = *(const float4*)xp;
  const float4 xb = *(const float4*)(xp + 4);
  bf16x8 a1;
  a1[0]=(__bf16)xa.x; a1[1]=(__bf16)xa.y; a1[2]=(__bf16)xa.z; a1[3]=(__bf16)xa.w;
  a1[4]=(__bf16)xb.x; a1[5]=(__bf16)xb.y; a1[6]=(__bf16)xb.z; a1[7]=(__bf16)xb.w;

#pragma unroll
  for (int i = 0; i < 4; ++i) {
    floatx4 acc = {0.f, 0.f, 0.f, 0.f};
    acc = mfma16(a1, b1f[i], acc);
#pragma unroll
    for (int r = 0; r < 4; ++r) {
      float v = fmaxf(acc[r] + b1v[i], 0.f);
      if (i == 3 && l16 == 15) v = 1.f;   // h1 col63 := 1 (layer-2 bias row)
      h1s[w][quad * 4 + r][i * 16 + l16] = v;
    }
  }
  __syncthreads();

  const float* hrow = &h1s[w][l16][0];
  const float4 p0 = *(const float4*)(hrow + quad * 8);
  const float4 p1 = *(const float4*)(hrow + quad * 8 + 4);
  const float4 p2 = *(const float4*)(hrow + 32 + quad * 8);
  const float4 p3 = *(const float4*)(hrow + 32 + quad * 8 + 4);
  bf16x8 a20, a21;
  a20[0]=(__bf16)p0.x; a20[1]=(__bf16)p0.y; a20[2]=(__bf16)p0.z; a20[3]=(__bf16)p0.w;
  a20[4]=(__bf16)p1.x; a20[5]=(__bf16)p1.y; a20[6]=(__bf16)p1.z; a20[7]=(__bf16)p1.w;
  a21[0]=(__bf16)p2.x; a21[1]=(__bf16)p2.y; a21[2]=(__bf16)p2.z; a21[3]=(__bf16)p2.w;
  a21[4]=(__bf16)p3.x; a21[5]=(__bf16)p3.y; a21[6]=(__bf16)p3.z; a21[7]=(__bf16)p3.w;

#pragma unroll
  for (int i = 0; i < 4; ++i) {
    floatx4 acc = {0.f, 0.f, 0.f, 0.f};
    acc = mfma16(a20, b2f[i][0], acc);
    acc = mfma16(a21, b2f[i][1], acc);  // bias via k=63 (h1 col63 == 1)
#pragma unroll
    for (int r = 0; r < 4; ++r)
      H[(size_t)(tok0 + quad * 4 + r) * 64 + i * 16 + l16] =
          (__bf16)fmaxf(acc[r], 0.f);
  }
}

// ---------------- Kernel B: fused logits-MFMA + exp/mask + pooling -----------
// Block = (n, 96-ch tile); barrier-free main loop, everything from global.
// XCD swizzle: the 21 tiles of one n share (bid & 7) -> same XCD's L2.
__global__ __launch_bounds__(256) void kern_att(
    const float* __restrict__ X, const float* __restrict__ Mk,
    const __bf16* __restrict__ H, const __bf16* __restrict__ W3fr,
    const float* __restrict__ Tb, float* __restrict__ out) {
  __shared__ float redS[4][96], redO[4][96];
  __shared__ float rbuf[96];

  const int bid = blockIdx.x;
  const int idx = bid >> 3;
  const int n = (bid & 7) * 16 + idx / 21;
  const int bt = idx % 21;
  const int tid = threadIdx.x;
  const int w = tid >> 6, lane = tid & 63, quad = lane >> 4, l16 = lane & 15;

  bf16x8 bf[6][2];
#pragma unroll
  for (int i = 0; i < 6; ++i) {
    bf[i][0] = *(const bf16x8*)(W3fr + ((((bt * 6 + i) * 2 + 0) * 16 + l16) * 4 + quad) * 8);
    bf[i][1] = *(const bf16x8*)(W3fr + ((((bt * 6 + i) * 2 + 1) * 16 + l16) * 4 + quad) * 8);
  }

  float s[6] = {0, 0, 0, 0, 0, 0}, o[6] = {0, 0, 0, 0, 0, 0};

#pragma unroll 1
  for (int it = 0; it < 8; ++it) {
    const int lw = it * 64 + w * 16;
    const __bf16* hp = H + (size_t)(n * LX_ + lw + l16) * 64;
    const bf16x8 a0 = *(const bf16x8*)(hp + quad * 8);
    const bf16x8 a1 = *(const bf16x8*)(hp + 32 + quad * 8);
    const float4 mk4 = *(const float4*)(Mk + n * LX_ + lw + quad * 4);
    const float* xrow = X + (size_t)(n * LX_ + lw + quad * 4) * D_;
    float xlo[4], xhi[4];
#pragma unroll
    for (int r = 0; r < 4; ++r) {
      xlo[r] = xrow[r * D_ + l16];        // d = l16      (even i tiles)
      xhi[r] = xrow[r * D_ + 16 + l16];   // d = 16+l16   (odd i tiles)
    }

#pragma unroll
    for (int i = 0; i < 6; ++i) {
      floatx4 acc = {0.f, 0.f, 0.f, 0.f};
      acc = mfma16(a0, bf[i][0], acc);
      acc = mfma16(a1, bf[i][1], acc);    // logit incl. b3 (k=63, H[:,63]==1)
      const float* xv = (i & 1) ? xhi : xlo;
      const float e0 = __expf(acc[0]) * mk4.x;
      const float e1 = __expf(acc[1]) * mk4.y;
      const float e2 = __expf(acc[2]) * mk4.z;
      const float e3 = __expf(acc[3]) * mk4.w;
      s[i] += (e0 + e1) + (e2 + e3);
      o[i] = fmaf(e0, xv[0], o[i]);
      o[i] = fmaf(e1, xv[1], o[i]);
      o[i] = fmaf(e2, xv[2], o[i]);
      o[i] = fmaf(e3, xv[3], o[i]);
    }
  }

  // reduce the 4 quads (row groups) within each wave
#pragma unroll
  for (int i = 0; i < 6; ++i) {
    s[i] += __shfl_xor(s[i], 16);
    s[i] += __shfl_xor(s[i], 32);
    o[i] += __shfl_xor(o[i], 16);
    o[i] += __shfl_xor(o[i], 32);
  }
  if (quad == 0) {
#pragma unroll
    for (int i = 0; i < 6; ++i) {
      redS[w][i * 16 + l16] = s[i];
      redO[w][i * 16 + l16] = o[i];
    }
  }
  __syncthreads();
  if (tid < 96) {
    const float S = redS[0][tid] + redS[1][tid] + redS[2][tid] + redS[3][tid];
    const float O = redO[0][tid] + redO[1][tid] + redO[2][tid] + redO[3][tid];
    rbuf[tid] = O / S;
  }
  __syncthreads();
  if (tid < 3) {
    float acc = 0.f;
#pragma unroll
    for (int dd = 0; dd < 32; ++dd) acc += rbuf[tid * 32 + dd];
    const int k = bt * 3 + tid;
    out[n * K_ + k] = fmaxf(acc + Tb[k], 0.f);
  }
}

extern "C" void kernel_launch(void* const* d_in, const int* in_sizes, int n_in,
                              void* d_out, int out_size, void* d_ws, size_t ws_size,
                              hipStream_t stream) {
  const float* X  = (const float*)d_in[0];
  const float* Mk = (const float*)d_in[1];
  const float* W1 = (const float*)d_in[2];
  const float* b1 = (const float*)d_in[3];
  const float* W2 = (const float*)d_in[4];
  const float* b2 = (const float*)d_in[5];
  const float* W3 = (const float*)d_in[6];
  const float* b3 = (const float*)d_in[7];
  const float* Tb = (const float*)d_in[8];
  float* out = (float*)d_out;

  char* ws = (char*)d_ws;
  __bf16* H     = (__bf16*)(ws + H_OFF);
  __bf16* W3fr  = (__bf16*)(ws + W3FR_OFF);
  __bf16* W1fr  = (__bf16*)(ws + W1FR_OFF);
  __bf16* W2fr  = (__bf16*)(ws + W2FR_OFF);
  float*  b1pad = (float*)(ws + B1_OFF);

  kern_prep<<<529, 256, 0, stream>>>(W1, b1, W2, b2, W3, b3, W3fr, W1fr, W2fr, b1pad);
  kern_mlp<<<N_ * LX_ / 64, 256, 0, stream>>>(X, W1fr, W2fr, b1pad, H);
  kern_att<<<N_ * 21, 256, 0, stream>>>(X, Mk, H, W3fr, Tb, out);
}

// Round 4
// 113.675 us; speedup vs baseline: 4.8818x; 1.1326x over previous
//
#include <hip/hip_runtime.h>
#include <hip/hip_bf16.h>

// TTCN: h=relu(X@W1+b1); h=relu(h@W2+b2); filt=h@W3+b3; masked softmax over Lx;
// out[n,k]=relu(sum_{l,d} X[n,l,d]*softmax(filt)[n,l,k,d] + T_bias[k])
// N=128, LX=512, D=32, K=63, C=2016.
// R4: mask compaction — masked rows contribute exactly 0 (exp(-1e8)==0), so we
// scan the mask per n (ballot+popc), compact H rows and X rows to the front,
// and kern_att only processes cnt[n] (~256) rows instead of 512. W3/b3 are
// pre-scaled by log2(e) so the epilogue is a raw v_exp_f32 (exp2). Biases ride
// the MFMA K-dim: h1[63]=1 & W2 row63=b2 => H[:,63]=1; W3fr row63=b3*log2e.

#define N_   128
#define LX_  512
#define D_   32
#define K_   63
#define C_   2016
#define LOG2E 1.44269504088896f

typedef __bf16 bf16x8 __attribute__((ext_vector_type(8)));
typedef float floatx4 __attribute__((ext_vector_type(4)));

static __device__ __forceinline__ floatx4 mfma16(bf16x8 a, bf16x8 b, floatx4 c) {
  return __builtin_amdgcn_mfma_f32_16x16x32_bf16(a, b, c, 0, 0, 0);
}

// ws layout (bytes)
#define HC_OFF   0u                        // 128n x 512row x 64 bf16 = 8 MiB (compacted)
#define XMC_OFF  (8u * 1024u * 1024u)      // 128n x 512row x 32 bf16 = 4 MiB (compacted X)
#define W3FR_OFF (12u * 1024u * 1024u)     // 129024 bf16 frag-packed, *log2e, row63=b3*log2e
#define W1FR_OFF (W3FR_OFF + 258048u)      // 2048 bf16
#define W2FR_OFF (W1FR_OFF + 4096u)        // 4096 bf16
#define B1_OFF   (W2FR_OFF + 8192u)        // 64 f32
#define POS_OFF  (B1_OFF + 256u)           // 65536 i32
#define CNT_OFF  (POS_OFF + 262144u)       // 128 i32

// ---------------- P: mask scan + pad-zeroing + weight frag packing -----------
__global__ __launch_bounds__(256) void kern_prep(
    const float* __restrict__ Mk,
    const float* __restrict__ W1, const float* __restrict__ b1,
    const float* __restrict__ W2, const float* __restrict__ b2,
    const float* __restrict__ W3, const float* __restrict__ b3,
    __bf16* __restrict__ W3fr, __bf16* __restrict__ W1fr,
    __bf16* __restrict__ W2fr, float* __restrict__ b1pad,
    int* __restrict__ pos, int* __restrict__ cnt,
    __bf16* __restrict__ Hc, __bf16* __restrict__ Xmc) {
  const int n = blockIdx.x, tid = threadIdx.x;
  __shared__ int s_cnt;

  if (tid < 64) {                       // wave 0: exclusive scan of the mask
    const int lane = tid;
    int running = 0;
    for (int c = 0; c < 8; ++c) {
      const int l = c * 64 + lane;
      const float mkv = Mk[n * LX_ + l];
      const unsigned long long b = __ballot(mkv > 0.5f);
      const int mypos = running + __popcll(b & ((1ull << lane) - 1ull));
      pos[n * LX_ + l] = (mkv > 0.5f) ? mypos : -1;
      running += __popcll(b);
    }
    if (lane == 0) { cnt[n] = running; s_cnt = running; }
  }
  __syncthreads();

  // zero padding rows [cnt, ceil64(cnt)) of Hc (8x16B/row) and Xmc (4x16B/row)
  const int c0 = s_cnt, c1 = (c0 + 63) & ~63;
  const float4 z = {0.f, 0.f, 0.f, 0.f};
  for (int idx = tid; idx < (c1 - c0) * 12; idx += 256) {
    const int row = c0 + idx / 12, q = idx % 12;
    if (q < 8) *(float4*)(Hc  + ((size_t)(n * 512 + row)) * 64 + q * 8) = z;
    else       *(float4*)(Xmc + ((size_t)(n * 512 + row)) * 32 + (q - 8) * 8) = z;
  }

  // weight packing (grid-stride over all slots)
  for (int g = n * 256 + tid; g < 129024 + 2048 + 4096 + 64; g += N_ * 256) {
    if (g < 129024) {                     // W3fr: [tile21][i6][h2][l16][quad][8], *log2e
      const int j = g & 7, quad = (g >> 3) & 3, l16 = (g >> 5) & 15, h = (g >> 9) & 1;
      const int rest = g >> 10, i = rest % 6, tile = rest / 6;
      const int c = tile * 96 + i * 16 + l16;
      const int t = h * 32 + quad * 8 + j;
      W3fr[g] = (__bf16)(((t < K_) ? W3[(size_t)t * C_ + c] : b3[c]) * LOG2E);
    } else if (g < 129024 + 2048) {       // W1fr: [i4][l16][quad][8]
      const int g2 = g - 129024;
      const int j = g2 & 7, quad = (g2 >> 3) & 3, l16 = (g2 >> 5) & 15, i = g2 >> 9;
      const int ch = i * 16 + l16, t = quad * 8 + j;
      W1fr[g2] = (__bf16)((ch < K_) ? W1[t * K_ + ch] : 0.f);
    } else if (g < 129024 + 2048 + 4096) {// W2fr: [i4][h2][l16][quad][8], row63=b2, [63][63]=1
      const int g2 = g - 129024 - 2048;
      const int j = g2 & 7, quad = (g2 >> 3) & 3, l16 = (g2 >> 5) & 15, h = (g2 >> 9) & 1;
      const int i = g2 >> 10;
      const int ch = i * 16 + l16, t = h * 32 + quad * 8 + j;
      float v;
      if (t < K_) v = (ch < K_) ? W2[t * K_ + ch] : 0.f;
      else        v = (ch < K_) ? b2[ch] : 1.f;
      W2fr[g2] = (__bf16)v;
    } else {
      const int g2 = g - 129024 - 2048 - 4096;
      b1pad[g2] = (g2 < K_) ? b1[g2] : 0.f;
    }
  }
}

// ---------------- M: Hc(bf16, compacted) = MLP(X); Xmc = compacted X ---------
// One 16-token tile per wave; barrier-free (per-wave LDS transpose only).
__global__ __launch_bounds__(256) void kern_mlp(
    const float* __restrict__ X, const __bf16* __restrict__ W1fr,
    const __bf16* __restrict__ W2fr, const float* __restrict__ b1pad,
    const int* __restrict__ pos, __bf16* __restrict__ Hc,
    __bf16* __restrict__ Xmc) {
  __shared__ float h1s[4][16][68];   // per-wave transpose tile
  const int tid = threadIdx.x;
  const int w = tid >> 6, lane = tid & 63, quad = lane >> 4, l16 = lane & 15;

  bf16x8 b1f[4], b2f[4][2];
  float b1v[4];
#pragma unroll
  for (int i = 0; i < 4; ++i) {
    b1f[i]    = *(const bf16x8*)(W1fr + ((i * 16 + l16) * 4 + quad) * 8);
    b2f[i][0] = *(const bf16x8*)(W2fr + (((i * 2 + 0) * 16 + l16) * 4 + quad) * 8);
    b2f[i][1] = *(const bf16x8*)(W2fr + (((i * 2 + 1) * 16 + l16) * 4 + quad) * 8);
    b1v[i] = b1pad[i * 16 + l16];
  }

  const int tok0 = blockIdx.x * 64 + w * 16;
  const int n = tok0 >> 9;
  const float* xp = X + (size_t)(tok0 + l16) * D_ + quad * 8;
  const float4 xa = *(const float4*)xp;
  const float4 xb = *(const float4*)(xp + 4);
  bf16x8 a1;
  a1[0]=(__bf16)xa.x; a1[1]=(__bf16)xa.y; a1[2]=(__bf16)xa.z; a1[3]=(__bf16)xa.w;
  a1[4]=(__bf16)xb.x; a1[5]=(__bf16)xb.y; a1[6]=(__bf16)xb.z; a1[7]=(__bf16)xb.w;

  // compaction indirection
  const int px = pos[tok0 + l16];
  int pr[4];
#pragma unroll
  for (int r = 0; r < 4; ++r) pr[r] = pos[tok0 + quad * 4 + r];

  if (px >= 0)   // compacted X row (mask==1 here, so X*mask == X)
    *(bf16x8*)(Xmc + ((size_t)(n * 512 + px)) * 32 + quad * 8) = a1;

#pragma unroll
  for (int i = 0; i < 4; ++i) {
    floatx4 acc = {0.f, 0.f, 0.f, 0.f};
    acc = mfma16(a1, b1f[i], acc);
#pragma unroll
    for (int r = 0; r < 4; ++r) {
      float v = fmaxf(acc[r] + b1v[i], 0.f);
      if (i == 3 && l16 == 15) v = 1.f;   // h1 col63 := 1 (layer-2 bias row)
      h1s[w][quad * 4 + r][i * 16 + l16] = v;
    }
  }
  // no barrier: h1s[w] is produced and consumed by the same wave (lgkmcnt orders)

  const float* hrow = &h1s[w][l16][0];
  const float4 p0 = *(const float4*)(hrow + quad * 8);
  const float4 p1 = *(const float4*)(hrow + quad * 8 + 4);
  const float4 p2 = *(const float4*)(hrow + 32 + quad * 8);
  const float4 p3 = *(const float4*)(hrow + 32 + quad * 8 + 4);
  bf16x8 a20, a21;
  a20[0]=(__bf16)p0.x; a20[1]=(__bf16)p0.y; a20[2]=(__bf16)p0.z; a20[3]=(__bf16)p0.w;
  a20[4]=(__bf16)p1.x; a20[5]=(__bf16)p1.y; a20[6]=(__bf16)p1.z; a20[7]=(__bf16)p1.w;
  a21[0]=(__bf16)p2.x; a21[1]=(__bf16)p2.y; a21[2]=(__bf16)p2.z; a21[3]=(__bf16)p2.w;
  a21[4]=(__bf16)p3.x; a21[5]=(__bf16)p3.y; a21[6]=(__bf16)p3.z; a21[7]=(__bf16)p3.w;

#pragma unroll
  for (int i = 0; i < 4; ++i) {
    floatx4 acc = {0.f, 0.f, 0.f, 0.f};
    acc = mfma16(a20, b2f[i][0], acc);
    acc = mfma16(a21, b2f[i][1], acc);  // bias via k=63 (h1 col63 == 1)
#pragma unroll
    for (int r = 0; r < 4; ++r) {
      if (pr[r] >= 0)
        Hc[((size_t)(n * 512 + pr[r])) * 64 + i * 16 + l16] =
            (__bf16)fmaxf(acc[r], 0.f);
    }
  }
}

// ---------------- A: fused logits-MFMA + exp2 + pooling (compacted rows) -----
// Block = (n, 96-ch tile); barrier-free main loop over ceil(cnt[n]/64) chunks,
// next-chunk loads prefetched. XCD swizzle groups one n's 21 tiles per XCD.
__global__ __launch_bounds__(256) void kern_att(
    const __bf16* __restrict__ Hc, const __bf16* __restrict__ Xmc,
    const __bf16* __restrict__ W3fr, const int* __restrict__ cnt,
    const float* __restrict__ Tb, float* __restrict__ out) {
  __shared__ float redS[4][96], redO[4][96];
  __shared__ float rbuf[96];

  const int bid = blockIdx.x;
  const int idx = bid >> 3;
  const int n = (bid & 7) * 16 + idx / 21;
  const int bt = idx % 21;
  const int tid = threadIdx.x;
  const int w = tid >> 6, lane = tid & 63, quad = lane >> 4, l16 = lane & 15;

  bf16x8 bf[6][2];
#pragma unroll
  for (int i = 0; i < 6; ++i) {
    bf[i][0] = *(const bf16x8*)(W3fr + ((((bt * 6 + i) * 2 + 0) * 16 + l16) * 4 + quad) * 8);
    bf[i][1] = *(const bf16x8*)(W3fr + ((((bt * 6 + i) * 2 + 1) * 16 + l16) * 4 + quad) * 8);
  }

  const int cntn = cnt[n];
  const int iters = (cntn + 63) >> 6;
  const __bf16* Hn = Hc + ((size_t)n << 9) * 64;
  const __bf16* Xn = Xmc + ((size_t)n << 9) * 32;

  float s[6] = {0, 0, 0, 0, 0, 0}, o[6] = {0, 0, 0, 0, 0, 0};

  int lw = w * 16;
  bf16x8 a0 = *(const bf16x8*)(Hn + (size_t)(lw + l16) * 64 + quad * 8);
  bf16x8 a1 = *(const bf16x8*)(Hn + (size_t)(lw + l16) * 64 + 32 + quad * 8);
  float xl[4], xh[4];
#pragma unroll
  for (int r = 0; r < 4; ++r) {
    xl[r] = (float)Xn[(lw + quad * 4 + r) * 32 + l16];
    xh[r] = (float)Xn[(lw + quad * 4 + r) * 32 + 16 + l16];
  }

#pragma unroll 1
  for (int it = 0;;) {
    bf16x8 na0, na1;
    float nxl[4], nxh[4];
    const int nlw = lw + 64;
    if (it + 1 < iters) {   // prefetch next chunk (wave-uniform branch)
      na0 = *(const bf16x8*)(Hn + (size_t)(nlw + l16) * 64 + quad * 8);
      na1 = *(const bf16x8*)(Hn + (size_t)(nlw + l16) * 64 + 32 + quad * 8);
#pragma unroll
      for (int r = 0; r < 4; ++r) {
        nxl[r] = (float)Xn[(nlw + quad * 4 + r) * 32 + l16];
        nxh[r] = (float)Xn[(nlw + quad * 4 + r) * 32 + 16 + l16];
      }
    }

    float v[4];   // row validity (pad rows: Hc=0 -> e=1, killed here; Xmc=0 protects o)
#pragma unroll
    for (int r = 0; r < 4; ++r) v[r] = (lw + quad * 4 + r < cntn) ? 1.f : 0.f;

#pragma unroll
    for (int i = 0; i < 6; ++i) {
      floatx4 acc = {0.f, 0.f, 0.f, 0.f};
      acc = mfma16(a0, bf[i][0], acc);
      acc = mfma16(a1, bf[i][1], acc);    // logit*log2e incl. b3 (k=63, H[:,63]==1)
      const float* xv = (i & 1) ? xh : xl;
#pragma unroll
      for (int r = 0; r < 4; ++r) {
        const float e = __builtin_amdgcn_exp2f(acc[r]);
        s[i] = fmaf(v[r], e, s[i]);
        o[i] = fmaf(e, xv[r], o[i]);
      }
    }

    if (++it >= iters) break;
    lw = nlw;
    a0 = na0; a1 = na1;
#pragma unroll
    for (int r = 0; r < 4; ++r) { xl[r] = nxl[r]; xh[r] = nxh[r]; }
  }

  // reduce the 4 quads (row groups) within each wave
#pragma unroll
  for (int i = 0; i < 6; ++i) {
    s[i] += __shfl_xor(s[i], 16);
    s[i] += __shfl_xor(s[i], 32);
    o[i] += __shfl_xor(o[i], 16);
    o[i] += __shfl_xor(o[i], 32);
  }
  if (quad == 0) {
#pragma unroll
    for (int i = 0; i < 6; ++i) {
      redS[w][i * 16 + l16] = s[i];
      redO[w][i * 16 + l16] = o[i];
    }
  }
  __syncthreads();
  if (tid < 96) {
    const float S = redS[0][tid] + redS[1][tid] + redS[2][tid] + redS[3][tid];
    const float O = redO[0][tid] + redO[1][tid] + redO[2][tid] + redO[3][tid];
    rbuf[tid] = O / S;
  }
  __syncthreads();
  if (tid < 3) {
    float acc = 0.f;
#pragma unroll
    for (int dd = 0; dd < 32; ++dd) acc += rbuf[tid * 32 + dd];
    const int k = bt * 3 + tid;
    out[n * K_ + k] = fmaxf(acc + Tb[k], 0.f);
  }
}

extern "C" void kernel_launch(void* const* d_in, const int* in_sizes, int n_in,
                              void* d_out, int out_size, void* d_ws, size_t ws_size,
                              hipStream_t stream) {
  const float* X  = (const float*)d_in[0];
  const float* Mk = (const float*)d_in[1];
  const float* W1 = (const float*)d_in[2];
  const float* b1 = (const float*)d_in[3];
  const float* W2 = (const float*)d_in[4];
  const float* b2 = (const float*)d_in[5];
  const float* W3 = (const float*)d_in[6];
  const float* b3 = (const float*)d_in[7];
  const float* Tb = (const float*)d_in[8];
  float* out = (float*)d_out;

  char* ws = (char*)d_ws;
  __bf16* Hc    = (__bf16*)(ws + HC_OFF);
  __bf16* Xmc   = (__bf16*)(ws + XMC_OFF);
  __bf16* W3fr  = (__bf16*)(ws + W3FR_OFF);
  __bf16* W1fr  = (__bf16*)(ws + W1FR_OFF);
  __bf16* W2fr  = (__bf16*)(ws + W2FR_OFF);
  float*  b1pad = (float*)(ws + B1_OFF);
  int*    pos   = (int*)(ws + POS_OFF);
  int*    cnt   = (int*)(ws + CNT_OFF);

  kern_prep<<<N_, 256, 0, stream>>>(Mk, W1, b1, W2, b2, W3, b3,
                                    W3fr, W1fr, W2fr, b1pad, pos, cnt, Hc, Xmc);
  kern_mlp<<<N_ * LX_ / 64, 256, 0, stream>>>(X, W1fr, W2fr, b1pad, pos, Hc, Xmc);
  kern_att<<<N_ * 21, 256, 0, stream>>>(Hc, Xmc, W3fr, cnt, Tb, out);
}

// Round 5
// 112.886 us; speedup vs baseline: 4.9159x; 1.0070x over previous
//
#include <hip/hip_runtime.h>
#include <hip/hip_bf16.h>

// TTCN: h=relu(X@W1+b1); h=relu(h@W2+b2); filt=h@W3+b3; masked softmax over Lx;
// out[n,k]=relu(sum_{l,d} X[n,l,d]*softmax(filt)[n,l,k,d] + T_bias[k])
// N=128, LX=512, D=32, K=63, C=2016.
// R5: mask compaction (masked rows contribute exactly 0) + pad-count trick:
// pad rows have H==0 -> logit==0 -> e==exp2(0)==1.0 exactly, so s accumulates
// unconditionally (v_pk_add_f32 pairs) and the scalar pad count is subtracted
// at the end. X is pre-transposed to f32 d-planes so the epilogue x-loads are
// 2 coalesced b128/wave. 16-row chunks round-robin over waves (tail waste ~5%).
// Biases ride the MFMA K-dim: h1[63]=1 & W2 row63=b2 => H[:,63]=1;
// W3fr row63 = b3*log2e (whole W3 prescaled by log2e -> raw v_exp_f32).

#define N_   128
#define LX_  512
#define D_   32
#define K_   63
#define C_   2016
#define LOG2E 1.44269504088896f

typedef __bf16 bf16x8 __attribute__((ext_vector_type(8)));
typedef float floatx4 __attribute__((ext_vector_type(4)));
typedef float floatx2 __attribute__((ext_vector_type(2)));

static __device__ __forceinline__ floatx4 mfma16(bf16x8 a, bf16x8 b, floatx4 c) {
  return __builtin_amdgcn_mfma_f32_16x16x32_bf16(a, b, c, 0, 0, 0);
}

// ws layout (bytes)
#define HC_OFF   0u                        // 128n x 512row x 64 bf16 = 8 MiB (compacted)
#define XT_OFF   (8u * 1024u * 1024u)      // 128n x 32chunk x 32d x 16row f32 = 8 MiB
#define W3FR_OFF (16u * 1024u * 1024u)     // 129024 bf16 frag-packed, *log2e, row63=b3*log2e
#define W1FR_OFF (W3FR_OFF + 258048u)      // 2048 bf16
#define W2FR_OFF (W1FR_OFF + 4096u)        // 4096 bf16
#define B1_OFF   (W2FR_OFF + 8192u)        // 64 f32
#define POS_OFF  (B1_OFF + 256u)           // 65536 i32
#define CNT_OFF  (POS_OFF + 262144u)       // 128 i32

// ---------------- P: mask scan + pad-zeroing + weight frag packing -----------
__global__ __launch_bounds__(256) void kern_prep(
    const float* __restrict__ Mk,
    const float* __restrict__ W1, const float* __restrict__ b1,
    const float* __restrict__ W2, const float* __restrict__ b2,
    const float* __restrict__ W3, const float* __restrict__ b3,
    __bf16* __restrict__ W3fr, __bf16* __restrict__ W1fr,
    __bf16* __restrict__ W2fr, float* __restrict__ b1pad,
    int* __restrict__ pos, int* __restrict__ cnt,
    __bf16* __restrict__ Hc, float* __restrict__ Xt) {
  const int n = blockIdx.x, tid = threadIdx.x;
  __shared__ int s_cnt;

  if (tid < 64) {                       // wave 0: exclusive scan of the mask
    const int lane = tid;
    int running = 0;
    for (int c = 0; c < 8; ++c) {
      const int l = c * 64 + lane;
      const float mkv = Mk[n * LX_ + l];
      const unsigned long long b = __ballot(mkv > 0.5f);
      const int mypos = running + __popcll(b & ((1ull << lane) - 1ull));
      pos[n * LX_ + l] = (mkv > 0.5f) ? mypos : -1;
      running += __popcll(b);
    }
    if (lane == 0) { cnt[n] = running; s_cnt = running; }
  }
  __syncthreads();

  // zero padding rows [cnt, ceil64(cnt)): Hc (8 float4/row) + Xt (32 dword/row)
  const int c0 = s_cnt, c1 = (c0 + 63) & ~63;
  const float4 z = {0.f, 0.f, 0.f, 0.f};
  for (int idx = tid; idx < (c1 - c0) * 40; idx += 256) {
    const int row = c0 + idx / 40, q = idx % 40;
    if (q < 8) {
      *(float4*)(Hc + ((size_t)(n * 512 + row)) * 64 + q * 8) = z;
    } else {
      const int d = q - 8;
      Xt[((size_t)(n * 32 + (row >> 4)) * 32 + d) * 16 + (row & 15)] = 0.f;
    }
  }

  // weight packing (grid-stride over all slots)
  for (int g = n * 256 + tid; g < 129024 + 2048 + 4096 + 64; g += N_ * 256) {
    if (g < 129024) {                     // W3fr: [tile21][i6][h2][l16][quad][8], *log2e
      const int j = g & 7, quad = (g >> 3) & 3, l16 = (g >> 5) & 15, h = (g >> 9) & 1;
      const int rest = g >> 10, i = rest % 6, tile = rest / 6;
      const int c = tile * 96 + i * 16 + l16;
      const int t = h * 32 + quad * 8 + j;
      W3fr[g] = (__bf16)(((t < K_) ? W3[(size_t)t * C_ + c] : b3[c]) * LOG2E);
    } else if (g < 129024 + 2048) {       // W1fr: [i4][l16][quad][8]
      const int g2 = g - 129024;
      const int j = g2 & 7, quad = (g2 >> 3) & 3, l16 = (g2 >> 5) & 15, i = g2 >> 9;
      const int ch = i * 16 + l16, t = quad * 8 + j;
      W1fr[g2] = (__bf16)((ch < K_) ? W1[t * K_ + ch] : 0.f);
    } else if (g < 129024 + 2048 + 4096) {// W2fr: [i4][h2][l16][quad][8], row63=b2, [63][63]=1
      const int g2 = g - 129024 - 2048;
      const int j = g2 & 7, quad = (g2 >> 3) & 3, l16 = (g2 >> 5) & 15, h = (g2 >> 9) & 1;
      const int i = g2 >> 10;
      const int ch = i * 16 + l16, t = h * 32 + quad * 8 + j;
      float v;
      if (t < K_) v = (ch < K_) ? W2[t * K_ + ch] : 0.f;
      else        v = (ch < K_) ? b2[ch] : 1.f;
      W2fr[g2] = (__bf16)v;
    } else {
      const int g2 = g - 129024 - 2048 - 4096;
      b1pad[g2] = (g2 < K_) ? b1[g2] : 0.f;
    }
  }
}

// ---------------- M: Hc(bf16, compacted) = MLP(X); Xt = compacted X planes ---
// One 16-token tile per wave; barrier-free (per-wave LDS transpose only).
__global__ __launch_bounds__(256) void kern_mlp(
    const float* __restrict__ X, const __bf16* __restrict__ W1fr,
    const __bf16* __restrict__ W2fr, const float* __restrict__ b1pad,
    const int* __restrict__ pos, __bf16* __restrict__ Hc,
    float* __restrict__ Xt) {
  __shared__ float h1s[4][16][68];   // per-wave transpose tile
  const int tid = threadIdx.x;
  const int w = tid >> 6, lane = tid & 63, quad = lane >> 4, l16 = lane & 15;

  bf16x8 b1f[4], b2f[4][2];
  float b1v[4];
#pragma unroll
  for (int i = 0; i < 4; ++i) {
    b1f[i]    = *(const bf16x8*)(W1fr + ((i * 16 + l16) * 4 + quad) * 8);
    b2f[i][0] = *(const bf16x8*)(W2fr + (((i * 2 + 0) * 16 + l16) * 4 + quad) * 8);
    b2f[i][1] = *(const bf16x8*)(W2fr + (((i * 2 + 1) * 16 + l16) * 4 + quad) * 8);
    b1v[i] = b1pad[i * 16 + l16];
  }

  const int tok0 = blockIdx.x * 64 + w * 16;
  const int n = tok0 >> 9;
  const float* xp = X + (size_t)(tok0 + l16) * D_ + quad * 8;
  const float4 xa = *(const float4*)xp;
  const float4 xb = *(const float4*)(xp + 4);
  bf16x8 a1;
  a1[0]=(__bf16)xa.x; a1[1]=(__bf16)xa.y; a1[2]=(__bf16)xa.z; a1[3]=(__bf16)xa.w;
  a1[4]=(__bf16)xb.x; a1[5]=(__bf16)xb.y; a1[6]=(__bf16)xb.z; a1[7]=(__bf16)xb.w;

  // compaction indirection
  const int px = pos[tok0 + l16];
  int pr[4];
#pragma unroll
  for (int r = 0; r < 4; ++r) pr[r] = pos[tok0 + quad * 4 + r];

  if (px >= 0) {  // compacted X f32 d-planes (mask==1 here, so X*mask == X)
    float* xtp = Xt + ((size_t)(n * 32 + (px >> 4)) * 32 + quad * 8) * 16 + (px & 15);
    const float vals[8] = {xa.x, xa.y, xa.z, xa.w, xb.x, xb.y, xb.z, xb.w};
#pragma unroll
    for (int j = 0; j < 8; ++j) xtp[j * 16] = vals[j];
  }

#pragma unroll
  for (int i = 0; i < 4; ++i) {
    floatx4 acc = {0.f, 0.f, 0.f, 0.f};
    acc = mfma16(a1, b1f[i], acc);
#pragma unroll
    for (int r = 0; r < 4; ++r) {
      float v = fmaxf(acc[r] + b1v[i], 0.f);
      if (i == 3 && l16 == 15) v = 1.f;   // h1 col63 := 1 (layer-2 bias row)
      h1s[w][quad * 4 + r][i * 16 + l16] = v;
    }
  }
  // no barrier: h1s[w] is produced and consumed by the same wave (lgkmcnt orders)

  const float* hrow = &h1s[w][l16][0];
  const float4 p0 = *(const float4*)(hrow + quad * 8);
  const float4 p1 = *(const float4*)(hrow + quad * 8 + 4);
  const float4 p2 = *(const float4*)(hrow + 32 + quad * 8);
  const float4 p3 = *(const float4*)(hrow + 32 + quad * 8 + 4);
  bf16x8 a20, a21;
  a20[0]=(__bf16)p0.x; a20[1]=(__bf16)p0.y; a20[2]=(__bf16)p0.z; a20[3]=(__bf16)p0.w;
  a20[4]=(__bf16)p1.x; a20[5]=(__bf16)p1.y; a20[6]=(__bf16)p1.z; a20[7]=(__bf16)p1.w;
  a21[0]=(__bf16)p2.x; a21[1]=(__bf16)p2.y; a21[2]=(__bf16)p2.z; a21[3]=(__bf16)p2.w;
  a21[4]=(__bf16)p3.x; a21[5]=(__bf16)p3.y; a21[6]=(__bf16)p3.z; a21[7]=(__bf16)p3.w;

#pragma unroll
  for (int i = 0; i < 4; ++i) {
    floatx4 acc = {0.f, 0.f, 0.f, 0.f};
    acc = mfma16(a20, b2f[i][0], acc);
    acc = mfma16(a21, b2f[i][1], acc);  // bias via k=63 (h1 col63 == 1)
#pragma unroll
    for (int r = 0; r < 4; ++r) {
      if (pr[r] >= 0)
        Hc[((size_t)(n * 512 + pr[r])) * 64 + i * 16 + l16] =
            (__bf16)fmaxf(acc[r], 0.f);
    }
  }
}

// ---------------- A: fused logits-MFMA + exp2 + pooling (compacted rows) -----
// Block = (n, 96-ch tile). 16-row chunks round-robin over waves (c = w; c += 4),
// software-pipelined 1 chunk deep. s accumulated unconditionally (pk_add pairs);
// pad rows contribute exactly 1.0 each, subtracted as a scalar at the end.
__global__ __launch_bounds__(256) void kern_att(
    const __bf16* __restrict__ Hc, const float* __restrict__ Xt,
    const __bf16* __restrict__ W3fr, const int* __restrict__ cnt,
    const float* __restrict__ Tb, float* __restrict__ out) {
  __shared__ float redS[4][96], redO[4][96];
  __shared__ float rbuf[96];

  const int bid = blockIdx.x;
  const int idx = bid >> 3;
  const int n = (bid & 7) * 16 + idx / 21;
  const int bt = idx % 21;
  const int tid = threadIdx.x;
  const int w = tid >> 6, lane = tid & 63, quad = lane >> 4, l16 = lane & 15;

  bf16x8 bf[6][2];
#pragma unroll
  for (int i = 0; i < 6; ++i) {
    bf[i][0] = *(const bf16x8*)(W3fr + ((((bt * 6 + i) * 2 + 0) * 16 + l16) * 4 + quad) * 8);
    bf[i][1] = *(const bf16x8*)(W3fr + ((((bt * 6 + i) * 2 + 1) * 16 + l16) * 4 + quad) * 8);
  }

  const int cntn = cnt[n];
  const int nch = (cntn + 15) >> 4;                 // 16-row chunks (~14..19)
  // lane base pointers; chunk c adds c*1024 (H, bf16) / c*512 (Xt, f32)
  const __bf16* Hb = Hc + ((size_t)n << 9) * 64 + (size_t)l16 * 64 + quad * 8;
  const float*  Xb = Xt + ((size_t)n * 32) * 512 + l16 * 16 + quad * 4;

  floatx2 s2[3] = {{0.f, 0.f}, {0.f, 0.f}, {0.f, 0.f}};
  float o[6] = {0, 0, 0, 0, 0, 0};

  int c = w;                                        // nch >= 13 >> 4, always valid
  bf16x8 a0 = *(const bf16x8*)(Hb + (size_t)c * 1024);
  bf16x8 a1 = *(const bf16x8*)(Hb + (size_t)c * 1024 + 32);
  float4 xl4 = *(const float4*)(Xb + c * 512);
  float4 xh4 = *(const float4*)(Xb + c * 512 + 256);

#pragma unroll 1
  while (c < nch) {
    const int cn = c + 4;
    bf16x8 na0, na1;
    float4 nxl, nxh;
    if (cn < nch) {                                 // wave-uniform prefetch
      na0 = *(const bf16x8*)(Hb + (size_t)cn * 1024);
      na1 = *(const bf16x8*)(Hb + (size_t)cn * 1024 + 32);
      nxl = *(const float4*)(Xb + cn * 512);
      nxh = *(const float4*)(Xb + cn * 512 + 256);
    }

#pragma unroll
    for (int t = 0; t < 3; ++t) {
      floatx4 accE = {0.f, 0.f, 0.f, 0.f};
      floatx4 accO = {0.f, 0.f, 0.f, 0.f};
      accE = mfma16(a0, bf[2 * t][0], accE);
      accE = mfma16(a1, bf[2 * t][1], accE);        // logit*log2e incl. b3
      accO = mfma16(a0, bf[2 * t + 1][0], accO);
      accO = mfma16(a1, bf[2 * t + 1][1], accO);
#pragma unroll
      for (int r = 0; r < 4; ++r) {
        floatx2 e2;
        e2.x = __builtin_amdgcn_exp2f(accE[r]);
        e2.y = __builtin_amdgcn_exp2f(accO[r]);
        s2[t] += e2;                                // pad rows add exactly 1.0
        o[2 * t]     = fmaf(e2.x, xl4[r], o[2 * t]);     // x==0 on pad rows
        o[2 * t + 1] = fmaf(e2.y, xh4[r], o[2 * t + 1]);
      }
    }

    c = cn;
    a0 = na0; a1 = na1; xl4 = nxl; xh4 = nxh;       // garbage on exit iter: unused
  }

  // reduce the 4 quads (row groups) within each wave
#pragma unroll
  for (int t = 0; t < 3; ++t) {
    s2[t].x += __shfl_xor(s2[t].x, 16); s2[t].x += __shfl_xor(s2[t].x, 32);
    s2[t].y += __shfl_xor(s2[t].y, 16); s2[t].y += __shfl_xor(s2[t].y, 32);
  }
#pragma unroll
  for (int i = 0; i < 6; ++i) {
    o[i] += __shfl_xor(o[i], 16);
    o[i] += __shfl_xor(o[i], 32);
  }
  if (quad == 0) {
#pragma unroll
    for (int t = 0; t < 3; ++t) {
      redS[w][(2 * t) * 16 + l16]     = s2[t].x;
      redS[w][(2 * t + 1) * 16 + l16] = s2[t].y;
    }
#pragma unroll
    for (int i = 0; i < 6; ++i) redO[w][i * 16 + l16] = o[i];
  }
  __syncthreads();
  if (tid < 96) {
    const float pad = (float)(nch * 16 - cntn);     // exact pad contribution to S
    const float S = redS[0][tid] + redS[1][tid] + redS[2][tid] + redS[3][tid] - pad;
    const float O = redO[0][tid] + redO[1][tid] + redO[2][tid] + redO[3][tid];
    rbuf[tid] = O / S;
  }
  __syncthreads();
  if (tid < 3) {
    float acc = 0.f;
#pragma unroll
    for (int dd = 0; dd < 32; ++dd) acc += rbuf[tid * 32 + dd];
    const int k = bt * 3 + tid;
    out[n * K_ + k] = fmaxf(acc + Tb[k], 0.f);
  }
}

extern "C" void kernel_launch(void* const* d_in, const int* in_sizes, int n_in,
                              void* d_out, int out_size, void* d_ws, size_t ws_size,
                              hipStream_t stream) {
  const float* X  = (const float*)d_in[0];
  const float* Mk = (const float*)d_in[1];
  const float* W1 = (const float*)d_in[2];
  const float* b1 = (const float*)d_in[3];
  const float* W2 = (const float*)d_in[4];
  const float* b2 = (const float*)d_in[5];
  const float* W3 = (const float*)d_in[6];
  const float* b3 = (const float*)d_in[7];
  const float* Tb = (const float*)d_in[8];
  float* out = (float*)d_out;

  char* ws = (char*)d_ws;
  __bf16* Hc    = (__bf16*)(ws + HC_OFF);
  float*  Xt    = (float*)(ws + XT_OFF);
  __bf16* W3fr  = (__bf16*)(ws + W3FR_OFF);
  __bf16* W1fr  = (__bf16*)(ws + W1FR_OFF);
  __bf16* W2fr  = (__bf16*)(ws + W2FR_OFF);
  float*  b1pad = (float*)(ws + B1_OFF);
  int*    pos   = (int*)(ws + POS_OFF);
  int*    cnt   = (int*)(ws + CNT_OFF);

  kern_prep<<<N_, 256, 0, stream>>>(Mk, W1, b1, W2, b2, W3, b3,
                                    W3fr, W1fr, W2fr, b1pad, pos, cnt, Hc, Xt);
  kern_mlp<<<N_ * LX_ / 64, 256, 0, stream>>>(X, W1fr, W2fr, b1pad, pos, Hc, Xt);
  kern_att<<<N_ * 21, 256, 0, stream>>>(Hc, Xt, W3fr, cnt, Tb, out);
}